// Round 1
// 130.894 us; speedup vs baseline: 1.0197x; 1.0197x over previous
//
#include <hip/hip_runtime.h>

#define IN_DIM   256
#define HID_DIM  512
#define OUT_DIM  256
#define N_CHILD  8
#define BATCH    1024

#define SB    16   // samples per chunk
#define XPAD  20   // [k][s] LDS stride: 16B-aligned float4 groups
#define MAXCH 128  // sum ceil(n_a/16) <= (1024 + 64*15)/16 = 124 < 128

// ---------------- prep: sort samples by agent + zero r_out ------------------
// grid (2): block 0 = counting sort + chunk list (wave-wide prefix scan);
// block 1 = zero r_out only (32 KB) — o_out is now written directly by k2.
extern "C" __global__ __launch_bounds__(1024)
void prep_sort(const int* __restrict__ raw, int* __restrict__ sorted,
               int* __restrict__ ch_agent, int* __restrict__ ch_start,
               int* __restrict__ ch_len, float* __restrict__ zdst)
{
    const int t = threadIdx.x;
    if (blockIdx.x > 0) {                         // zero r_out: 2048 float4
        const int total4 = (BATCH * N_CHILD) / 4;
        const float4 z = make_float4(0.f, 0.f, 0.f, 0.f);
        for (int i = t; i < total4; i += 1024)
            ((float4*)zdst)[i] = z;
        return;
    }
    __shared__ int cnt[64], cnt2[64], start[64];
    __shared__ int is32, totch;
    if (t < 64) { cnt[t] = 0; cnt2[t] = 0; }
    if (t == 0) is32 = 0;
    __syncthreads();
    if (raw[2 * (t & 511) + 1] != 0) is32 = 1;   // benign shared race
    __syncthreads();
    const int a = (is32 ? raw[t] : raw[2 * t]) & 63;
    atomicAdd(&cnt[a], 1);
    __syncthreads();
    if (t < 64) {                                 // wave 0: dual prefix scan
        const int c   = cnt[t];
        const int nch = (c + SB - 1) / SB;
        int sc = c, sn = nch;
        #pragma unroll
        for (int d = 1; d < 64; d <<= 1) {
            const int vc = __shfl_up(sc, d);
            const int vn = __shfl_up(sn, d);
            if (t >= d) { sc += vc; sn += vn; }
        }
        const int off = sc - c;
        start[t] = off;
        const int chb = sn - nch;
        for (int p = 0, j = 0; p < c; p += SB, ++j) {
            ch_agent[chb + j] = t;
            ch_start[chb + j] = off + p;
            ch_len[chb + j]   = (c - p < SB) ? (c - p) : SB;
        }
        if (t == 63) totch = sn;
    }
    __syncthreads();
    if (t >= totch && t < MAXCH) ch_len[t] = 0;
    const int pos = start[a] + atomicAdd(&cnt2[a], 1);
    sorted[pos] = t;
}

// ---------------- K1: H = relu(X @ W1[a] + b1[a]); R += H @ rw[a] -----------
// grid (MAXCH, 8 tiles of 64 cols), 256 thr = 4 waves. LDS 36.9 KB -> 4 blk/CU.
// ASYNC-SPLIT staging: next-pass W tile is loaded into registers BEFORE the
// compute phase; the loop-top barrier (vmcnt drain) lands after compute, so
// global-load latency overlaps the FMA loop instead of serializing per pass.
extern "C" __global__ __launch_bounds__(256)
void k1_mlp1(const float* __restrict__ x, const float* __restrict__ W1,
             const float* __restrict__ b1, const float* __restrict__ rw,
             const int* __restrict__ sorted, const int* __restrict__ ch_agent,
             const int* __restrict__ ch_start, const int* __restrict__ ch_len,
             float* __restrict__ h_out, float* __restrict__ r_out)
{
    const int chunk = blockIdx.x;
    const int len = ch_len[chunk];
    if (len == 0) return;
    const int a  = ch_agent[chunk];
    const int cs = ch_start[chunk];
    const int t  = threadIdx.x;
    const int bcol = blockIdx.y * 64;

    __shared__ float xT[IN_DIM * XPAD];      // 20 KB, [k][s], staged once
    __shared__ float wS[64 * 64];            // 16 KB, single LDS buffer
    __shared__ int   sid[SB];

    if (t < SB) sid[t] = sorted[cs + (t < len ? t : len - 1)];   // pad = dup
    __syncthreads();

    const float* Wb = W1 + (size_t)a * IN_DIM * HID_DIM + bcol;
    const int sr  = t >> 4;                  // staging row base (0..15)
    const int sc4 = (t & 15) * 4;            // staging col
    #define WLD(P,I) (*(const float4*)(Wb + (size_t)((P)*64 + sr + (I)*16) * HID_DIM + sc4))

    // issue pass-0 W loads, then x staging (all in flight together)
    float4 wr0 = WLD(0,0), wr1 = WLD(0,1), wr2 = WLD(0,2), wr3 = WLD(0,3);

    #pragma unroll
    for (int s = 0; s < SB; ++s)
        xT[t * XPAD + s] = x[(size_t)sid[s] * IN_DIM + t];       // coalesced

    const int cg = t & 15;
    const int kq = (t >> 4) & 3;
    const int w  = t >> 6;
    const bool act = (w * 4) < len;

    float acc[16];
    #pragma unroll
    for (int i = 0; i < 16; ++i) acc[i] = 0.f;

    for (int p = 0; p < IN_DIM / 64; ++p) {  // 4 passes of 64 k-rows
        __syncthreads();                     // wS free; covers xT at p==0
        *(float4*)(&wS[(sr +  0) * 64 + sc4]) = wr0;
        *(float4*)(&wS[(sr + 16) * 64 + sc4]) = wr1;
        *(float4*)(&wS[(sr + 32) * 64 + sc4]) = wr2;
        *(float4*)(&wS[(sr + 48) * 64 + sc4]) = wr3;
        __syncthreads();
        if (p < 3) {                         // prefetch next tile -> regs
            wr0 = WLD(p+1,0); wr1 = WLD(p+1,1);
            wr2 = WLD(p+1,2); wr3 = WLD(p+1,3);
        }
        if (act) {
            #pragma unroll
            for (int i = 0; i < 16; ++i) {
                const int row = i * 4 + kq;  // kq-contiguous: bank spread
                const float4 wv = *(const float4*)(&wS[row * 64 + cg * 4]);
                const float4 xv = *(const float4*)(&xT[(p * 64 + row) * XPAD + w * 4]);
                const float wa[4] = {wv.x, wv.y, wv.z, wv.w};
                const float xa[4] = {xv.x, xv.y, xv.z, xv.w};
                #pragma unroll
                for (int c = 0; c < 4; ++c)
                    #pragma unroll
                    for (int s = 0; s < 4; ++s)
                        acc[c * 4 + s] = fmaf(wa[c], xa[s], acc[c * 4 + s]);
            }
        }
    }
    #undef WLD

    if (!act) return;

    #pragma unroll
    for (int i = 0; i < 16; ++i) {           // reduce over kq (lane bits 4-5)
        acc[i] += __shfl_xor(acc[i], 16);
        acc[i] += __shfl_xor(acc[i], 32);
    }

    if (kq != 0) return;                     // epilogue on kq==0 lanes only

    const float4 bv = *(const float4*)(b1 + a * HID_DIM + bcol + cg * 4);
    const float ba[4] = {bv.x, bv.y, bv.z, bv.w};
    float hv[16];
    #pragma unroll
    for (int c = 0; c < 4; ++c)
        #pragma unroll
        for (int s = 0; s < 4; ++s)
            hv[c * 4 + s] = fmaxf(acc[c * 4 + s] + ba[c], 0.f);

    #pragma unroll
    for (int s = 0; s < 4; ++s) {            // dup-slot writes identical
        float4 v = make_float4(hv[0 * 4 + s], hv[1 * 4 + s],
                               hv[2 * 4 + s], hv[3 * 4 + s]);
        *(float4*)(h_out + (size_t)sid[w * 4 + s] * HID_DIM + bcol + cg * 4) = v;
    }

    float rp[32];                            // router partials [s][ch]
    #pragma unroll
    for (int i = 0; i < 32; ++i) rp[i] = 0.f;
    const float* rwa = rw + (size_t)a * HID_DIM * N_CHILD
                          + (size_t)(bcol + cg * 4) * N_CHILD;
    #pragma unroll
    for (int j = 0; j < 4; ++j)
        #pragma unroll
        for (int ch = 0; ch < 8; ++ch) {
            const float rv = rwa[j * N_CHILD + ch];
            #pragma unroll
            for (int s = 0; s < 4; ++s)
                rp[s * 8 + ch] = fmaf(hv[j * 4 + s], rv, rp[s * 8 + ch]);
        }
    #pragma unroll
    for (int i = 0; i < 32; ++i) {           // reduce over cg (lane bits 0-3)
        rp[i] += __shfl_xor(rp[i], 1);
        rp[i] += __shfl_xor(rp[i], 2);
        rp[i] += __shfl_xor(rp[i], 4);
        rp[i] += __shfl_xor(rp[i], 8);
    }
    if (cg == 0) {
        #pragma unroll
        for (int s = 0; s < 4; ++s) {
            const int sg = w * 4 + s;
            if (sg < len) {                  // strict gating for atomics
                float* rdst = r_out + (size_t)sid[sg] * N_CHILD;
                #pragma unroll
                for (int ch = 0; ch < 8; ++ch)
                    atomicAdd(rdst + ch, rp[s * 8 + ch]);
            }
        }
    }
}

// ---------------- K2: OUT = H @ W2[a] + b2[a]  (full K=512 per block) -------
// grid (MAXCH, 4 tiles of 64 cols), 256 thr. LDS 21.3 KB -> 7 blk/CU.
// Full-K accumulation -> direct float4 stores, NO atomics, no o_out zeroing.
// Same async-split prefetch for both the h tile and the W tile.
extern "C" __global__ __launch_bounds__(256)
void k2_mlp2(const float* __restrict__ h, const float* __restrict__ W2,
             const float* __restrict__ b2,
             const int* __restrict__ sorted, const int* __restrict__ ch_agent,
             const int* __restrict__ ch_start, const int* __restrict__ ch_len,
             float* __restrict__ o_out)
{
    const int chunk = blockIdx.x;
    const int len = ch_len[chunk];
    if (len == 0) return;
    const int a  = ch_agent[chunk];
    const int cs = ch_start[chunk];
    const int t  = threadIdx.x;
    const int bcol = blockIdx.y * 64;

    __shared__ float hT[64 * XPAD];          // 5 KB, per-pass h tile
    __shared__ float wS[64 * 64];            // 16 KB, per-pass W tile
    __shared__ int   sid[SB];

    if (t < SB) sid[t] = sorted[cs + (t < len ? t : len - 1)];
    __syncthreads();

    const float* Wb = W2 + (size_t)a * HID_DIM * OUT_DIM + bcol;
    const int sr   = t >> 4;
    const int sc4  = (t & 15) * 4;
    const int hrow = t & 63;                 // h staging: 64 consecutive k
    const int hsb  = (t >> 6) * 4;           // 4 samples per wave-group
    #define WLD2(P,I) (*(const float4*)(Wb + (size_t)((P)*64 + sr + (I)*16) * OUT_DIM + sc4))
    #define HLD(P,J)  (h[(size_t)sid[hsb + (J)] * HID_DIM + (P)*64 + hrow])

    float4 wr0 = WLD2(0,0), wr1 = WLD2(0,1), wr2 = WLD2(0,2), wr3 = WLD2(0,3);
    float  hr0 = HLD(0,0),  hr1 = HLD(0,1),  hr2 = HLD(0,2),  hr3 = HLD(0,3);

    const int cg = t & 15;
    const int kq = (t >> 4) & 3;
    const int w  = t >> 6;
    const bool act = (w * 4) < len;

    float acc[16];
    #pragma unroll
    for (int i = 0; i < 16; ++i) acc[i] = 0.f;

    for (int p = 0; p < HID_DIM / 64; ++p) { // 8 passes over full K
        __syncthreads();                     // tiles free
        hT[hrow * XPAD + hsb + 0] = hr0;
        hT[hrow * XPAD + hsb + 1] = hr1;
        hT[hrow * XPAD + hsb + 2] = hr2;
        hT[hrow * XPAD + hsb + 3] = hr3;
        *(float4*)(&wS[(sr +  0) * 64 + sc4]) = wr0;
        *(float4*)(&wS[(sr + 16) * 64 + sc4]) = wr1;
        *(float4*)(&wS[(sr + 32) * 64 + sc4]) = wr2;
        *(float4*)(&wS[(sr + 48) * 64 + sc4]) = wr3;
        __syncthreads();
        if (p < 7) {                         // prefetch next tiles -> regs
            wr0 = WLD2(p+1,0); wr1 = WLD2(p+1,1);
            wr2 = WLD2(p+1,2); wr3 = WLD2(p+1,3);
            hr0 = HLD(p+1,0);  hr1 = HLD(p+1,1);
            hr2 = HLD(p+1,2);  hr3 = HLD(p+1,3);
        }
        if (act) {
            #pragma unroll
            for (int i = 0; i < 16; ++i) {
                const int row = i * 4 + kq;  // kq-contiguous: bank spread
                const float4 wv = *(const float4*)(&wS[row * 64 + cg * 4]);
                const float4 xv = *(const float4*)(&hT[row * XPAD + w * 4]);
                const float wa[4] = {wv.x, wv.y, wv.z, wv.w};
                const float xa[4] = {xv.x, xv.y, xv.z, xv.w};
                #pragma unroll
                for (int c = 0; c < 4; ++c)
                    #pragma unroll
                    for (int s = 0; s < 4; ++s)
                        acc[c * 4 + s] = fmaf(wa[c], xa[s], acc[c * 4 + s]);
            }
        }
    }
    #undef WLD2
    #undef HLD

    if (!act) return;
    #pragma unroll
    for (int i = 0; i < 16; ++i) {
        acc[i] += __shfl_xor(acc[i], 16);
        acc[i] += __shfl_xor(acc[i], 32);
    }
    if (kq == 0) {
        const float4 bv = *(const float4*)(b2 + a * OUT_DIM + bcol + cg * 4);
        #pragma unroll
        for (int s = 0; s < 4; ++s) {
            const int g = w * 4 + s;
            if (g < len) {                   // strict gating: one writer/row
                float4 v = make_float4(acc[0 * 4 + s] + bv.x,
                                       acc[1 * 4 + s] + bv.y,
                                       acc[2 * 4 + s] + bv.z,
                                       acc[3 * 4 + s] + bv.w);
                *(float4*)(o_out + (size_t)sid[g] * OUT_DIM + bcol + cg * 4) = v;
            }
        }
    }
}

extern "C" void kernel_launch(void* const* d_in, const int* in_sizes, int n_in,
                              void* d_out, int out_size, void* d_ws, size_t ws_size,
                              hipStream_t stream) {
    const float* x  = (const float*)d_in[0];
    const float* W1 = (const float*)d_in[1];
    const float* b1 = (const float*)d_in[2];
    const float* W2 = (const float*)d_in[3];
    const float* b2 = (const float*)d_in[4];
    const float* rw = (const float*)d_in[5];
    const int* raw  = (const int*)d_in[6];

    int* ws       = (int*)d_ws;
    int* sorted   = ws;            // [1024]
    int* ch_agent = ws + 1024;     // [128]
    int* ch_start = ws + 1152;     // [128]
    int* ch_len   = ws + 1280;     // [128]

    float* out   = (float*)d_out;
    float* h_out = out;                                   // [B, HID]
    float* o_out = h_out + (size_t)BATCH * HID_DIM;       // [B, OUT]
    float* r_out = o_out + (size_t)BATCH * OUT_DIM;       // [B, C]

    hipLaunchKernelGGL(prep_sort, dim3(2), dim3(1024), 0, stream,
                       raw, sorted, ch_agent, ch_start, ch_len, r_out);
    hipLaunchKernelGGL(k1_mlp1, dim3(MAXCH, 8), dim3(256), 0, stream,
                       x, W1, b1, rw, sorted, ch_agent, ch_start, ch_len,
                       h_out, r_out);
    hipLaunchKernelGGL(k2_mlp2, dim3(MAXCH, 4), dim3(256), 0, stream,
                       h_out, W2, b2, sorted, ch_agent, ch_start, ch_len, o_out);
}

// Round 2
// 129.576 us; speedup vs baseline: 1.0300x; 1.0102x over previous
//
#include <hip/hip_runtime.h>

#define IN_DIM   256
#define HID_DIM  512
#define OUT_DIM  256
#define N_CHILD  8
#define BATCH    1024

#define SB    16   // samples per chunk
#define XPAD  20   // [k][s] LDS stride: 16B-aligned float4 groups
#define MAXCH 128  // sum ceil(n_a/16) <= (1024 + 64*15)/16 = 124 < 128

// ---------------- fused per-block chunk derivation (replaces prep kernel) ---
// Every block recomputes the counting sort deterministically from raw ids:
// histogram via shared atomics (order-independent counts), chunk table via
// wave-0 prefix scan over ceil(cnt/16), stable sample ranks via 256-thread
// prefix scan of per-thread match counts (thread order = index order).
// All blocks derive IDENTICAL chunk->samples maps: no inter-block traffic.
// Returns len (0 => this block has no work). Agent id left in s_info[0].
__device__ __forceinline__ int sort_chunk(const int* __restrict__ raw, const int c,
                                          int* s_cnt, int* s_info, int* s_wsum,
                                          int* s_sid)
{
    const int t = threadIdx.x;           // 256 threads
    const int lane = t & 63, w = t >> 6;
    if (t < 64) s_cnt[t] = 0;
    if (t == 0) { s_info[2] = 0; s_info[3] = 0; }
    __syncthreads();
    // int32 vs int64 agent_indices: odd 32-bit words of first 1024 ints
    if (raw[2 * t + 1] != 0 || raw[2 * (t + 256) + 1] != 0) s_info[3] = 1;
    __syncthreads();
    const int is32 = s_info[3];
    int myid[4];
    #pragma unroll
    for (int j = 0; j < 4; ++j) {
        const int i = t * 4 + j;
        const int v = (is32 ? raw[i] : raw[2 * i]) & 63;
        myid[j] = v;
        atomicAdd(&s_cnt[v], 1);
    }
    __syncthreads();
    if (t < 64) {                        // wave 0: chunk table prefix scan
        const int ca  = s_cnt[t];
        const int nch = (ca + SB - 1) / SB;
        int sn = nch;
        #pragma unroll
        for (int d = 1; d < 64; d <<= 1) {
            const int v = __shfl_up(sn, d);
            if (lane >= d) sn += v;
        }
        const int chb = sn - nch;        // exclusive: first chunk of agent t
        if (c >= chb && c < chb + nch) { // exactly one agent claims chunk c
            s_info[0] = t;
            const int p = (c - chb) * SB;
            s_info[1] = p;
            s_info[2] = (ca - p < SB) ? (ca - p) : SB;
        }
    }
    __syncthreads();
    const int len = s_info[2];
    if (len == 0) return 0;              // uniform: c >= total chunks
    const int a = s_info[0], p = s_info[1];
    int m = 0;
    #pragma unroll
    for (int j = 0; j < 4; ++j) if (myid[j] == a) ++m;
    int inc = m;                         // inclusive wave scan of match counts
    #pragma unroll
    for (int d = 1; d < 64; d <<= 1) {
        const int v = __shfl_up(inc, d);
        if (lane >= d) inc += v;
    }
    if (lane == 63) s_wsum[w] = inc;
    __syncthreads();
    int base = inc - m;                  // exclusive rank base
    #pragma unroll
    for (int ww = 0; ww < 4; ++ww) if (ww < w) base += s_wsum[ww];
    #pragma unroll
    for (int j = 0; j < 4; ++j)
        if (myid[j] == a) {              // stable rank among agent's samples
            const int r = (base++) - p;
            if (r >= 0 && r < SB) s_sid[r] = t * 4 + j;
        }
    __syncthreads();
    if (t >= len && t < SB) s_sid[t] = s_sid[len - 1];   // pad = dup
    __syncthreads();
    return len;
}

// ---------------- K1: H = relu(X @ W1[a] + b1[a]); router partials -> ws ----
// grid (MAXCH, 8 tiles of 64 cols), 256 thr. LDS 36.4 KB -> 4 blk/CU, all
// 1024 blocks co-resident. Register-prefetched single-LDS-buffer staging.
// Router: per-(chunk,y) partials stored (no atomics, no zeroing); k2 sums.
extern "C" __global__ __launch_bounds__(256)
void k1_mlp1(const float* __restrict__ x, const float* __restrict__ W1,
             const float* __restrict__ b1, const float* __restrict__ rw,
             const int* __restrict__ raw,
             float* __restrict__ h_out, float* __restrict__ r_part)
{
    __shared__ float xT[IN_DIM * XPAD];  // 20 KB, [k][s]
    __shared__ float wS[64 * 64];        // 16 KB W tile
    __shared__ int s_cnt[64], s_info[4], s_wsum[4], s_sid[SB];

    const int chunk = blockIdx.x;
    const int t = threadIdx.x;
    const int len = sort_chunk(raw, chunk, s_cnt, s_info, s_wsum, s_sid);
    if (len == 0) return;
    const int a    = s_info[0];
    const int bcol = blockIdx.y * 64;

    const float* Wb = W1 + (size_t)a * IN_DIM * HID_DIM + bcol;
    const int sr  = t >> 4;
    const int sc4 = (t & 15) * 4;
    #define WLD(P,I) (*(const float4*)(Wb + (size_t)((P)*64 + sr + (I)*16) * HID_DIM + sc4))

    float4 wr0 = WLD(0,0), wr1 = WLD(0,1), wr2 = WLD(0,2), wr3 = WLD(0,3);

    #pragma unroll
    for (int s = 0; s < SB; ++s)
        xT[t * XPAD + s] = x[(size_t)s_sid[s] * IN_DIM + t];     // coalesced

    const int cg = t & 15;
    const int kq = (t >> 4) & 3;
    const int w  = t >> 6;
    const bool act = (w * 4) < len;

    float acc[16];
    #pragma unroll
    for (int i = 0; i < 16; ++i) acc[i] = 0.f;

    for (int p = 0; p < IN_DIM / 64; ++p) {
        __syncthreads();                 // wS free; covers xT at p==0
        *(float4*)(&wS[(sr +  0) * 64 + sc4]) = wr0;
        *(float4*)(&wS[(sr + 16) * 64 + sc4]) = wr1;
        *(float4*)(&wS[(sr + 32) * 64 + sc4]) = wr2;
        *(float4*)(&wS[(sr + 48) * 64 + sc4]) = wr3;
        __syncthreads();
        if (p < 3) {
            wr0 = WLD(p+1,0); wr1 = WLD(p+1,1);
            wr2 = WLD(p+1,2); wr3 = WLD(p+1,3);
        }
        if (act) {
            #pragma unroll
            for (int i = 0; i < 16; ++i) {
                const int row = i * 4 + kq;
                const float4 wv = *(const float4*)(&wS[row * 64 + cg * 4]);
                const float4 xv = *(const float4*)(&xT[(p * 64 + row) * XPAD + w * 4]);
                const float wa[4] = {wv.x, wv.y, wv.z, wv.w};
                const float xa[4] = {xv.x, xv.y, xv.z, xv.w};
                #pragma unroll
                for (int c = 0; c < 4; ++c)
                    #pragma unroll
                    for (int s = 0; s < 4; ++s)
                        acc[c * 4 + s] = fmaf(wa[c], xa[s], acc[c * 4 + s]);
            }
        }
    }
    #undef WLD

    if (!act) return;
    #pragma unroll
    for (int i = 0; i < 16; ++i) {       // reduce over kq (lane bits 4-5)
        acc[i] += __shfl_xor(acc[i], 16);
        acc[i] += __shfl_xor(acc[i], 32);
    }
    if (kq != 0) return;

    const float4 bv = *(const float4*)(b1 + a * HID_DIM + bcol + cg * 4);
    const float ba[4] = {bv.x, bv.y, bv.z, bv.w};
    float hv[16];
    #pragma unroll
    for (int c = 0; c < 4; ++c)
        #pragma unroll
        for (int s = 0; s < 4; ++s)
            hv[c * 4 + s] = fmaxf(acc[c * 4 + s] + ba[c], 0.f);

    #pragma unroll
    for (int s = 0; s < 4; ++s) {        // dup-slot writes identical
        float4 v = make_float4(hv[0 * 4 + s], hv[1 * 4 + s],
                               hv[2 * 4 + s], hv[3 * 4 + s]);
        *(float4*)(h_out + (size_t)s_sid[w * 4 + s] * HID_DIM + bcol + cg * 4) = v;
    }

    float rp[32];                        // router partials [s][ch]
    #pragma unroll
    for (int i = 0; i < 32; ++i) rp[i] = 0.f;
    const float* rwa = rw + (size_t)a * HID_DIM * N_CHILD
                          + (size_t)(bcol + cg * 4) * N_CHILD;
    #pragma unroll
    for (int j = 0; j < 4; ++j)
        #pragma unroll
        for (int ch = 0; ch < 8; ++ch) {
            const float rv = rwa[j * N_CHILD + ch];
            #pragma unroll
            for (int s = 0; s < 4; ++s)
                rp[s * 8 + ch] = fmaf(hv[j * 4 + s], rv, rp[s * 8 + ch]);
        }
    #pragma unroll
    for (int i = 0; i < 32; ++i) {       // reduce over cg (lane bits 0-3)
        rp[i] += __shfl_xor(rp[i], 1);
        rp[i] += __shfl_xor(rp[i], 2);
        rp[i] += __shfl_xor(rp[i], 4);
        rp[i] += __shfl_xor(rp[i], 8);
    }
    if (cg == 0) {                       // direct partial store, no atomics
        float* rb = r_part + ((size_t)chunk * 8 + blockIdx.y) * 128 + w * 32;
        #pragma unroll
        for (int s4 = 0; s4 < 8; ++s4)
            *(float4*)(rb + s4 * 4) = make_float4(rp[s4*4+0], rp[s4*4+1],
                                                  rp[s4*4+2], rp[s4*4+3]);
    }
}

// ---------------- K2: OUT = H @ W2[a] + b2[a]; router final sum -------------
// grid (MAXCH, 8 tiles of 32 cols), 256 thr. LDS 13.6 KB -> high occupancy,
// 1024 blocks (was 512): halves the tail. Full-K accumulation, direct float4
// stores (no atomics). 8-way K-split lanes: cg=t&7 (4 cols), kq=(t>>3)&7.
// y==0 block also sums k1's router partials -> r_out (no zeroing needed).
extern "C" __global__ __launch_bounds__(256)
void k2_mlp2(const float* __restrict__ h, const float* __restrict__ W2,
             const float* __restrict__ b2, const int* __restrict__ raw,
             const float* __restrict__ r_part,
             float* __restrict__ o_out, float* __restrict__ r_out)
{
    __shared__ float hT[64 * XPAD];      // 5 KB per-pass h tile
    __shared__ float wS[64 * 32];        // 8 KB per-pass W tile
    __shared__ int s_cnt[64], s_info[4], s_wsum[4], s_sid[SB];

    const int chunk = blockIdx.x;
    const int t = threadIdx.x;
    const int len = sort_chunk(raw, chunk, s_cnt, s_info, s_wsum, s_sid);
    if (len == 0) return;
    const int a    = s_info[0];
    const int bcol = blockIdx.y * 32;

    const float* Wb = W2 + (size_t)a * HID_DIM * OUT_DIM + bcol;
    const int r2   = t >> 3;             // staging row 0..31
    const int c4   = (t & 7) * 4;        // staging col
    const int hrow = t & 63;
    const int hsb  = (t >> 6) * 4;
    #define WLD2(P,I) (*(const float4*)(Wb + (size_t)((P)*64 + r2 + (I)*32) * OUT_DIM + c4))
    #define HLD(P,J)  (h[(size_t)s_sid[hsb + (J)] * HID_DIM + (P)*64 + hrow])

    float4 wr0 = WLD2(0,0), wr1 = WLD2(0,1);
    float  hr0 = HLD(0,0), hr1 = HLD(0,1), hr2 = HLD(0,2), hr3 = HLD(0,3);

    const int cg = t & 7;
    const int kq = (t >> 3) & 7;
    const int w  = t >> 6;
    const bool act = (w * 4) < len;

    float acc[16];
    #pragma unroll
    for (int i = 0; i < 16; ++i) acc[i] = 0.f;

    for (int p = 0; p < HID_DIM / 64; ++p) {
        __syncthreads();
        hT[hrow * XPAD + hsb + 0] = hr0;
        hT[hrow * XPAD + hsb + 1] = hr1;
        hT[hrow * XPAD + hsb + 2] = hr2;
        hT[hrow * XPAD + hsb + 3] = hr3;
        *(float4*)(&wS[(r2 +  0) * 32 + c4]) = wr0;
        *(float4*)(&wS[(r2 + 32) * 32 + c4]) = wr1;
        __syncthreads();
        if (p < 7) {
            wr0 = WLD2(p+1,0); wr1 = WLD2(p+1,1);
            hr0 = HLD(p+1,0);  hr1 = HLD(p+1,1);
            hr2 = HLD(p+1,2);  hr3 = HLD(p+1,3);
        }
        if (act) {
            #pragma unroll
            for (int i = 0; i < 8; ++i) {
                const int row = i * 8 + kq;  // kq-spread rows: conflict-free
                const float4 wv = *(const float4*)(&wS[row * 32 + cg * 4]);
                const float4 xv = *(const float4*)(&hT[row * XPAD + w * 4]);
                const float wa[4] = {wv.x, wv.y, wv.z, wv.w};
                const float xa[4] = {xv.x, xv.y, xv.z, xv.w};
                #pragma unroll
                for (int c = 0; c < 4; ++c)
                    #pragma unroll
                    for (int s = 0; s < 4; ++s)
                        acc[c * 4 + s] = fmaf(wa[c], xa[s], acc[c * 4 + s]);
            }
        }
    }
    #undef WLD2
    #undef HLD

    #pragma unroll
    for (int i = 0; i < 16; ++i) {       // reduce over kq (lane bits 3-5)
        acc[i] += __shfl_xor(acc[i], 8);
        acc[i] += __shfl_xor(acc[i], 16);
        acc[i] += __shfl_xor(acc[i], 32);
    }
    if (act && kq == 0) {
        const float4 bv = *(const float4*)(b2 + a * OUT_DIM + bcol + cg * 4);
        #pragma unroll
        for (int s = 0; s < 4; ++s) {
            const int g = w * 4 + s;
            if (g < len) {               // strict gating: one writer per row
                float4 v = make_float4(acc[0 * 4 + s] + bv.x,
                                       acc[1 * 4 + s] + bv.y,
                                       acc[2 * 4 + s] + bv.z,
                                       acc[3 * 4 + s] + bv.w);
                *(float4*)(o_out + (size_t)s_sid[g] * OUT_DIM + bcol + cg * 4) = v;
            }
        }
    }
    if (blockIdx.y == 0 && t < 128) {    // router final: sum 8 partials
        const int s = t >> 3;
        if (s < len) {
            float sum = 0.f;
            #pragma unroll
            for (int yy = 0; yy < 8; ++yy)
                sum += r_part[((size_t)chunk * 8 + yy) * 128 + t];
            r_out[(size_t)s_sid[s] * N_CHILD + (t & 7)] = sum;
        }
    }
}

extern "C" void kernel_launch(void* const* d_in, const int* in_sizes, int n_in,
                              void* d_out, int out_size, void* d_ws, size_t ws_size,
                              hipStream_t stream) {
    const float* x  = (const float*)d_in[0];
    const float* W1 = (const float*)d_in[1];
    const float* b1 = (const float*)d_in[2];
    const float* W2 = (const float*)d_in[3];
    const float* b2 = (const float*)d_in[4];
    const float* rw = (const float*)d_in[5];
    const int* raw  = (const int*)d_in[6];

    float* r_part = (float*)d_ws;        // [MAXCH][8][16][8] = 512 KB

    float* out   = (float*)d_out;
    float* h_out = out;                                   // [B, HID]
    float* o_out = h_out + (size_t)BATCH * HID_DIM;       // [B, OUT]
    float* r_out = o_out + (size_t)BATCH * OUT_DIM;       // [B, C]

    hipLaunchKernelGGL(k1_mlp1, dim3(MAXCH, 8), dim3(256), 0, stream,
                       x, W1, b1, rw, raw, h_out, r_part);
    hipLaunchKernelGGL(k2_mlp2, dim3(MAXCH, 8), dim3(256), 0, stream,
                       h_out, W2, b2, raw, r_part, o_out, r_out);
}